// Round 5
// baseline (64.929 us; speedup 1.0000x reference)
//
#include <hip/hip_runtime.h>
#include <hip/hip_bf16.h>

// out = conv13(in @ M^T),  M = Wout @ Win   (conv commutes with the channel GEMMs)
// g(d) = N(0,1) pdf; |d|<=6 truncation error ~1e-8.
// R5: all-blocks-resident (LDS 48KB -> 3 blocks/CU >= grid 588), A single-buffer
//     + 2 barriers/step, sliding-window conv epilogue with uniform edge branch.

typedef unsigned short u16;
typedef unsigned int u32;
typedef unsigned long long u64;
typedef __attribute__((ext_vector_type(8))) short bf16x8;
typedef __attribute__((ext_vector_type(8))) unsigned short u16x8;
typedef __attribute__((ext_vector_type(4))) unsigned short u16x4;
typedef __attribute__((ext_vector_type(4))) float f32x4;
typedef __attribute__((ext_vector_type(2))) u32 u32x2;

typedef __attribute__((address_space(1))) const void* as1_cvp;
typedef __attribute__((address_space(3))) void* as3_vp;

#define EDIM 512
#define SEQ  4096
#define NROW 16384
#define ROWS_OUT 112
#define MBLK ((NROW + ROWS_OUT - 1) / ROWS_OUT)  // 147
#define NWG (MBLK * 4)                            // 588
#define BK 64
#define NKT 8
// LDS u16 offsets: A (single) at 0 (8192), B0 at 8192, B1 at 16384. 49152 B total.
#define LB0 8192
#define YSTR 136

__device__ __forceinline__ float b2f(u16 x) {
  union { u32 u; float f; } c; c.u = ((u32)x) << 16; return c.f;
}
__device__ __forceinline__ u16 f2b(float x) {
  union { float f; u32 u; } c; c.f = x;
  return (u16)((c.u + 0x7fffu + ((c.u >> 16) & 1u)) >> 16);  // RNE
}
__device__ __forceinline__ u32 cvtpk(float lo, float hi) {
  u32 r;
  asm("v_cvt_pk_bf16_f32 %0, %1, %2" : "=v"(r) : "v"(lo), "v"(hi));
  return r;
}
__device__ __forceinline__ void async_cp16(const void* g, void* l) {
  __builtin_amdgcn_global_load_lds((as1_cvp)(u64)g, (as3_vp)(u32)(u64)l, 16, 0, 0);
}

// ---------------------------------------------------------------------------
// Kernel 1: M[f,e] = sum_c Wout[f,c] * Win[c,e]  (512^3), fp32 in, bf16 out.
// ---------------------------------------------------------------------------
__global__ __launch_bounds__(256) void gemm_m(const float* __restrict__ Wout,
                                              const float* __restrict__ Win,
                                              u16* __restrict__ Mm) {
  __shared__ u16 la[64 * 32];
  __shared__ u16 lbt[64 * 32];
  int t = threadIdx.x;
  int w = t >> 6, l = t & 63, lr = l & 15, lk = l >> 4;
  int f0 = (int)(blockIdx.x >> 3) * 64, e0 = (int)(blockIdx.x & 7) * 64;
  f32x4 acc[4] = {};
  for (int kt = 0; kt < 16; ++kt) {
    int k0 = kt * 32;
    __syncthreads();
    {
      const float* src = Wout + (u64)(f0 + (t >> 2)) * EDIM + k0 + (t & 3) * 8;
      u16x8 o;
#pragma unroll
      for (int j = 0; j < 8; ++j) o[j] = f2b(src[j]);
      *(u16x8*)(la + (t >> 2) * 32 + (t & 3) * 8) = o;
    }
    {
      const float* src = Win + (u64)(k0 + (t >> 3)) * EDIM + e0 + (t & 7) * 8;
#pragma unroll
      for (int j = 0; j < 8; ++j) lbt[((t & 7) * 8 + j) * 32 + (t >> 3)] = f2b(src[j]);
    }
    __syncthreads();
    bf16x8 a = *(const bf16x8*)(la + (w * 16 + lr) * 32 + lk * 8);
#pragma unroll
    for (int ni = 0; ni < 4; ++ni) {
      bf16x8 b = *(const bf16x8*)(lbt + (ni * 16 + lr) * 32 + lk * 8);
      acc[ni] = __builtin_amdgcn_mfma_f32_16x16x32_bf16(a, b, acc[ni], 0, 0, 0);
    }
  }
#pragma unroll
  for (int ni = 0; ni < 4; ++ni)
#pragma unroll
    for (int r = 0; r < 4; ++r)
      Mm[(u64)(f0 + w * 16 + lk * 4 + r) * EDIM + e0 + ni * 16 + lr] = f2b(acc[ni][r]);
}

// ---------------------------------------------------------------------------
// Sliding-window 13-tap conv from Y[128][136] bf16 in LDS -> fp32 out.
// Thread: 4 cols (qc=t&31), 14 consecutive rows (grp=t>>5, rl0=8+grp*14).
// EDGE: block's tap range crosses a batch boundary (or array end) -> mask taps.
// ---------------------------------------------------------------------------
template <bool EDGE>
__device__ __forceinline__ void conv_store(const u16* __restrict__ Y, int t,
                                           int m0c, int n0, float* __restrict__ out) {
  const float G[7] = {0.39894228040143270f, 0.24197072451914337f,
                      0.053990966513188063f, 0.0044318484119380075f,
                      1.3383022576488537e-4f, 1.4867195147342977e-6f,
                      6.0758828498232861e-9f};
  int qc = t & 31, grp = t >> 5;
  int rl0 = 8 + grp * 14;
  const u16* Yb = Y + qc * 4;
  f32x4 wnd[13];
#pragma unroll
  for (int i = 0; i < 13; ++i) {
    u16x4 yv = *(const u16x4*)(Yb + (rl0 - 6 + i) * YSTR);
#pragma unroll
    for (int q = 0; q < 4; ++q) wnd[i][q] = b2f(yv[q]);
  }
#pragma unroll
  for (int j = 0; j < 14; ++j) {
    int rl = rl0 + j, rg = m0c + rl;
    f32x4 a = {};
#pragma unroll
    for (int d = -6; d <= 6; ++d) {
      float g = G[d < 0 ? -d : d];
      if (EDGE) {
        int rt = rg + d;
        g = ((rt >> 12) == (rg >> 12)) ? g : 0.0f;
      }
#pragma unroll
      for (int q = 0; q < 4; ++q) a[q] += g * wnd[d + 6][q];
    }
    if (!EDGE || rg < NROW)
      *(f32x4*)(out + (u64)rg * EDIM + n0 + qc * 4) = a;
    if (j < 13) {
#pragma unroll
      for (int i = 0; i < 12; ++i) wnd[i] = wnd[i + 1];
      u16x4 yv = *(const u16x4*)(Yb + (rl + 7) * YSTR);
#pragma unroll
      for (int q = 0; q < 4; ++q) wnd[12][q] = b2f(yv[q]);
    }
  }
}

// ---------------------------------------------------------------------------
// Kernel 2: fused GEMM + conv epilogue.
// 128x128 tile, BK=64, A single-buffer (reg-staged, cvt_pk), B double-buffer
// (global_load_lds w16, pre-swizzled source). 48KB LDS -> 3 blocks/CU; grid
// 588 <= 768 slots -> every block resident, single residency wave.
// ---------------------------------------------------------------------------
__global__ __launch_bounds__(256) void fused_gc(const float* __restrict__ in,
                                                const u16* __restrict__ Mm,
                                                float* __restrict__ out) {
  __shared__ u16 lds[24576];  // 48 KB; Y[128][136]=34.8KB reuses the front
  int t = threadIdx.x;
  int l = t & 63, lr = l & 15, lk = l >> 4;
  int wv = t >> 6, wr = wv >> 1, wc = wv & 1;

  // bijective XCD swizzle (m204): the 4 n-blocks of one m-panel share an XCD L2
  int b = (int)blockIdx.x;
  int q = NWG >> 3, r = NWG & 7;  // 73, 4
  int xcd = b & 7, off = b >> 3;
  int wg = (xcd < r ? xcd * (q + 1) : r * (q + 1) + (xcd - r) * q) + off;
  int ib = wg >> 2;
  int n0 = (wg & 3) << 7;
  int m0c = ib * ROWS_OUT - 8;

  // A source rows (clamped at array ends); lane: 4 fp32 x 8 row-groups
  u32 rowoff[8];
#pragma unroll
  for (int j = 0; j < 8; ++j) {
    int rg = m0c + j * 16 + (t >> 4);
    rg = rg < 0 ? 0 : (rg > NROW - 1 ? NROW - 1 : rg);
    rowoff[j] = (u32)rg * EDIM + (t & 15) * 4;
  }
  // B global source, octet pre-swizzled so LDS-linear dest holds swizzled layout
  const u16* gB = Mm + (u64)(n0 + (t >> 3)) * EDIM + (((t & 7) ^ ((t >> 3) & 7)) * 8);

  int aw_idx[8];
#pragma unroll
  for (int j = 0; j < 8; ++j) {
    int row = j * 16 + (t >> 4);
    aw_idx[j] = (row * 64 + (t & 15) * 4) ^ ((row & 7) << 3);
  }
  int ard[4], brd[4];
#pragma unroll
  for (int mi = 0; mi < 4; ++mi) {
    int row = wr * 64 + mi * 16 + lr;
    ard[mi] = (row * 64 + lk * 8) ^ ((row & 7) << 3);
  }
#pragma unroll
  for (int ni = 0; ni < 4; ++ni) {
    int row = wc * 64 + ni * 16 + lr;
    brd[ni] = (row * 64 + lk * 8) ^ ((row & 7) << 3);
  }

  f32x4 acc[4][4] = {};
  f32x4 ar[8];

  // ---- prologue: stage tile 0 (A -> regs -> LDS; B -> async LDS buf0)
#pragma unroll
  for (int j = 0; j < 8; ++j) ar[j] = *(const f32x4*)(in + rowoff[j]);
#pragma unroll
  for (int i = 0; i < 4; ++i)
    async_cp16(gB + (u64)i * 32 * EDIM, lds + LB0 + t * 8 + i * 2048);
#pragma unroll
  for (int j = 0; j < 8; ++j) {
    u32x2 p;
    p[0] = cvtpk(ar[j][0], ar[j][1]);
    p[1] = cvtpk(ar[j][2], ar[j][3]);
    *(u32x2*)(lds + aw_idx[j]) = p;
  }
  __syncthreads();

  int cur = 0;
  for (int kt = 0; kt < NKT; ++kt) {
    int nxt = cur ^ 1;
    if (kt < NKT - 1) {  // issue next-tile loads BEFORE compute
      int k1 = (kt + 1) * BK;
#pragma unroll
      for (int j = 0; j < 8; ++j) ar[j] = *(const f32x4*)(in + rowoff[j] + k1);
#pragma unroll
      for (int i = 0; i < 4; ++i)
        async_cp16(gB + k1 + (u64)i * 32 * EDIM,
                   lds + LB0 + nxt * 8192 + t * 8 + i * 2048);
    }
    int bbase = LB0 + cur * 8192;
#pragma unroll
    for (int kk = 0; kk < 64; kk += 32) {
      bf16x8 af[4], bfr[4];
#pragma unroll
      for (int mi = 0; mi < 4; ++mi)
        af[mi] = *(const bf16x8*)(lds + (ard[mi] ^ kk));
#pragma unroll
      for (int ni = 0; ni < 4; ++ni)
        bfr[ni] = *(const bf16x8*)(lds + bbase + (brd[ni] ^ kk));
#pragma unroll
      for (int mi = 0; mi < 4; ++mi)
#pragma unroll
        for (int ni = 0; ni < 4; ++ni)
          acc[mi][ni] = __builtin_amdgcn_mfma_f32_16x16x32_bf16(af[mi], bfr[ni],
                                                                acc[mi][ni], 0, 0, 0);
    }
    __syncthreads();  // all reads of A-lds done (also drains in-flight loads)
    if (kt < NKT - 1) {
#pragma unroll
      for (int j = 0; j < 8; ++j) {
        u32x2 p;
        p[0] = cvtpk(ar[j][0], ar[j][1]);
        p[1] = cvtpk(ar[j][2], ar[j][3]);
        *(u32x2*)(lds + aw_idx[j]) = p;
      }
    }
    __syncthreads();  // A-lds (and B[nxt]) ready for next step
    cur = nxt;
  }

  // ---- epilogue: acc -> Y[128][136] bf16 in LDS, then sliding-window conv
  u16* Y = lds;
#pragma unroll
  for (int mi = 0; mi < 4; ++mi)
#pragma unroll
    for (int ni = 0; ni < 4; ++ni)
#pragma unroll
      for (int rr = 0; rr < 4; ++rr)
        Y[(wr * 64 + mi * 16 + lk * 4 + rr) * YSTR + wc * 64 + ni * 16 + lr] =
            f2b(acc[mi][ni][rr]);
  __syncthreads();

  bool edge = ((m0c + 2) >> 12) != ((m0c + 125) >> 12);
  if (edge)
    conv_store<true>(Y, t, m0c, n0, out);
  else
    conv_store<false>(Y, t, m0c, n0, out);
}

extern "C" void kernel_launch(void* const* d_in, const int* in_sizes, int n_in,
                              void* d_out, int out_size, void* d_ws, size_t ws_size,
                              hipStream_t stream) {
  const float* in   = (const float*)d_in[0];
  const float* Win  = (const float*)d_in[1];
  const float* Wout = (const float*)d_in[2];
  float* outp = (float*)d_out;

  u16* Mm = (u16*)d_ws;

  hipLaunchKernelGGL(gemm_m,   dim3(64), dim3(256), 0, stream, Wout, Win, Mm);
  hipLaunchKernelGGL(fused_gc, dim3(NWG), dim3(256), 0, stream, in, Mm, outp);
}

// Round 6
// 39.147 us; speedup vs baseline: 1.6586x; 1.6586x over previous
//
#include <hip/hip_runtime.h>
#include <hip/hip_bf16.h>

// out = conv13(in @ M^T),  M = Wout @ Win   (conv commutes with the channel GEMMs)
// g(d) = N(0,1) pdf; |d|<=6 truncation error ~1e-8.
// R6: raw s_barrier + counted s_waitcnt pipeline (m201 idiom) so prefetched
//     loads stay in flight across barriers (fix the __syncthreads vmcnt(0) drain);
//     gemm_m rewritten BK=64 with reg-prefetch overlap.

typedef unsigned short u16;
typedef unsigned int u32;
typedef unsigned long long u64;
typedef __attribute__((ext_vector_type(8))) short bf16x8;
typedef __attribute__((ext_vector_type(8))) unsigned short u16x8;
typedef __attribute__((ext_vector_type(4))) unsigned short u16x4;
typedef __attribute__((ext_vector_type(4))) float f32x4;
typedef __attribute__((ext_vector_type(2))) u32 u32x2;

typedef __attribute__((address_space(1))) const void* as1_cvp;
typedef __attribute__((address_space(3))) void* as3_vp;

#define EDIM 512
#define SEQ  4096
#define NROW 16384
#define ROWS_OUT 112
#define MBLK ((NROW + ROWS_OUT - 1) / ROWS_OUT)  // 147
#define NWG (MBLK * 4)                            // 588
#define BK 64
#define NKT 8
#define LB0 8192   // u16 offset of B buffers (A: 0..8191, B0: 8192.., B1: 16384..)
#define YSTR 136

__device__ __forceinline__ float b2f(u16 x) {
  union { u32 u; float f; } c; c.u = ((u32)x) << 16; return c.f;
}
__device__ __forceinline__ u16 f2b(float x) {
  union { float f; u32 u; } c; c.f = x;
  return (u16)((c.u + 0x7fffu + ((c.u >> 16) & 1u)) >> 16);  // RNE
}
__device__ __forceinline__ u32 cvtpk(float lo, float hi) {
  u32 r;
  asm("v_cvt_pk_bf16_f32 %0, %1, %2" : "=v"(r) : "v"(lo), "v"(hi));
  return r;
}
__device__ __forceinline__ void async_cp16(const void* g, void* l) {
  __builtin_amdgcn_global_load_lds((as1_cvp)(u64)g, (as3_vp)(u32)(u64)l, 16, 0, 0);
}

// ---------------------------------------------------------------------------
// Kernel 1: M[f,e] = sum_c Wout[f,c] * Win[c,e]  (512^3), fp32 in, bf16 out.
// 64 blocks, 64x64 tile, BK=64, 8 steps, reg-prefetch overlap. Strides 72
// (16B-aligned rows, conflict-light).
// ---------------------------------------------------------------------------
__global__ __launch_bounds__(256) void gemm_m(const float* __restrict__ Wout,
                                              const float* __restrict__ Win,
                                              u16* __restrict__ Mm) {
  __shared__ u16 la[64 * 72];
  __shared__ u16 lbt[64 * 72];
  int t = threadIdx.x;
  int w = t >> 6, l = t & 63, lr = l & 15, lk = l >> 4;
  int f0 = (int)(blockIdx.x >> 3) * 64, e0 = (int)(blockIdx.x & 7) * 64;
  int arow = t >> 2, acol = (t & 3) * 16;
  const float* pA = Wout + (u64)(f0 + arow) * EDIM + acol;   // A rows f, cols c
  const float* pB = Win + (u64)arow * EDIM + e0 + acol;      // B rows c, cols e
  f32x4 a4[4], b4[4];
  f32x4 acc[4] = {};
#pragma unroll
  for (int i = 0; i < 4; ++i) { a4[i] = *(const f32x4*)(pA + i * 4); b4[i] = *(const f32x4*)(pB + i * 4); }
  for (int kt = 0; kt < 8; ++kt) {
    // write staged regs -> LDS (prev compute's reads were fenced by loop-end barrier)
    u16x8 av0, av1;
#pragma unroll
    for (int q = 0; q < 4; ++q) { av0[q] = f2b(a4[0][q]); av0[4 + q] = f2b(a4[1][q]); }
#pragma unroll
    for (int q = 0; q < 4; ++q) { av1[q] = f2b(a4[2][q]); av1[4 + q] = f2b(a4[3][q]); }
    *(u16x8*)(la + arow * 72 + acol) = av0;
    *(u16x8*)(la + arow * 72 + acol + 8) = av1;
#pragma unroll
    for (int j = 0; j < 16; ++j)
      lbt[(acol + j) * 72 + arow] = f2b(b4[j >> 2][j & 3]);   // transpose scatter [e][c]
    __syncthreads();
    if (kt < 7) {
      pA += 64; pB += (u64)64 * EDIM;
#pragma unroll
      for (int i = 0; i < 4; ++i) { a4[i] = *(const f32x4*)(pA + i * 4); b4[i] = *(const f32x4*)(pB + i * 4); }
    }
#pragma unroll
    for (int kk = 0; kk < 64; kk += 32) {
      bf16x8 a = *(const bf16x8*)(la + (w * 16 + lr) * 72 + kk + lk * 8);
#pragma unroll
      for (int ni = 0; ni < 4; ++ni) {
        bf16x8 bfv = *(const bf16x8*)(lbt + (ni * 16 + lr) * 72 + kk + lk * 8);
        acc[ni] = __builtin_amdgcn_mfma_f32_16x16x32_bf16(a, bfv, acc[ni], 0, 0, 0);
      }
    }
    __syncthreads();
  }
#pragma unroll
  for (int ni = 0; ni < 4; ++ni)
#pragma unroll
    for (int r = 0; r < 4; ++r)
      Mm[(u64)(f0 + w * 16 + lk * 4 + r) * EDIM + e0 + ni * 16 + lr] = f2b(acc[ni][r]);
}

// ---------------------------------------------------------------------------
// Sliding-window 13-tap conv from Y[128][136] bf16 in LDS -> fp32 out.
// ---------------------------------------------------------------------------
template <bool EDGE>
__device__ __forceinline__ void conv_store(const u16* __restrict__ Y, int t,
                                           int m0c, int n0, float* __restrict__ out) {
  const float G[7] = {0.39894228040143270f, 0.24197072451914337f,
                      0.053990966513188063f, 0.0044318484119380075f,
                      1.3383022576488537e-4f, 1.4867195147342977e-6f,
                      6.0758828498232861e-9f};
  int qc = t & 31, grp = t >> 5;
  int rl0 = 8 + grp * 14;
  const u16* Yb = Y + qc * 4;
  f32x4 wnd[13];
#pragma unroll
  for (int i = 0; i < 13; ++i) {
    u16x4 yv = *(const u16x4*)(Yb + (rl0 - 6 + i) * YSTR);
#pragma unroll
    for (int q = 0; q < 4; ++q) wnd[i][q] = b2f(yv[q]);
  }
#pragma unroll
  for (int j = 0; j < 14; ++j) {
    int rl = rl0 + j, rg = m0c + rl;
    f32x4 a = {};
#pragma unroll
    for (int d = -6; d <= 6; ++d) {
      float g = G[d < 0 ? -d : d];
      if (EDGE) {
        int rt = rg + d;
        g = ((rt >> 12) == (rg >> 12)) ? g : 0.0f;
      }
#pragma unroll
      for (int q = 0; q < 4; ++q) a[q] += g * wnd[d + 6][q];
    }
    if (!EDGE || rg < NROW)
      *(f32x4*)(out + (u64)rg * EDIM + n0 + qc * 4) = a;
    if (j < 13) {
#pragma unroll
      for (int i = 0; i < 12; ++i) wnd[i] = wnd[i + 1];
      u16x4 yv = *(const u16x4*)(Yb + (rl + 7) * YSTR);
#pragma unroll
      for (int q = 0; q < 4; ++q) wnd[12][q] = b2f(yv[q]);
    }
  }
}

// ---------------------------------------------------------------------------
// Kernel 2: fused GEMM + conv epilogue, raw-barrier counted-wait pipeline.
// Per step: vmcnt(0) [only cur B-tile in flight] ; issue next A-glb(8)+B-async(4);
// s_barrier ; ds_read+MFMA ; s_barrier ; cvt+ds_write A ; lgkmcnt(0).
// The 12 prefetched loads stay in flight across both barriers (no drain).
// ---------------------------------------------------------------------------
__global__ __launch_bounds__(256, 3) void fused_gc(const float* __restrict__ in,
                                                   const u16* __restrict__ Mm,
                                                   float* __restrict__ out) {
  __shared__ u16 lds[24576];  // 48 KB: A 16KB | B0 16KB | B1 16KB ; Y overlays front
  int t = threadIdx.x;
  int l = t & 63, lr = l & 15, lk = l >> 4;
  int wv = t >> 6, wr = wv >> 1, wc = wv & 1;

  // bijective XCD swizzle (m204)
  int b = (int)blockIdx.x;
  int q = NWG >> 3, r = NWG & 7;  // 73, 4
  int xcd = b & 7, off = b >> 3;
  int wg = (xcd < r ? xcd * (q + 1) : r * (q + 1) + (xcd - r) * q) + off;
  int ib = wg >> 2;
  int n0 = (wg & 3) << 7;
  int m0c = ib * ROWS_OUT - 8;

  u32 rowoff[8];
#pragma unroll
  for (int j = 0; j < 8; ++j) {
    int rg = m0c + j * 16 + (t >> 4);
    rg = rg < 0 ? 0 : (rg > NROW - 1 ? NROW - 1 : rg);
    rowoff[j] = (u32)rg * EDIM + (t & 15) * 4;
  }
  const u16* gB = Mm + (u64)(n0 + (t >> 3)) * EDIM + (((t & 7) ^ ((t >> 3) & 7)) * 8);

  int aw_idx[8];
#pragma unroll
  for (int j = 0; j < 8; ++j) {
    int row = j * 16 + (t >> 4);
    aw_idx[j] = (row * 64 + (t & 15) * 4) ^ ((row & 7) << 3);
  }
  int ard[4], brd[4];
#pragma unroll
  for (int mi = 0; mi < 4; ++mi) {
    int row = wr * 64 + mi * 16 + lr;
    ard[mi] = (row * 64 + lk * 8) ^ ((row & 7) << 3);
  }
#pragma unroll
  for (int ni = 0; ni < 4; ++ni) {
    int row = wc * 64 + ni * 16 + lr;
    brd[ni] = (row * 64 + lk * 8) ^ ((row & 7) << 3);
  }

  f32x4 acc[4][4] = {};
  f32x4 ar[8];

  // ---- prologue: stage tile 0
#pragma unroll
  for (int j = 0; j < 8; ++j) ar[j] = *(const f32x4*)(in + rowoff[j]);
#pragma unroll
  for (int i = 0; i < 4; ++i)
    async_cp16(gB + (u64)i * 32 * EDIM, lds + LB0 + t * 8 + i * 2048);
#pragma unroll
  for (int j = 0; j < 8; ++j) {   // compiler auto-waits the 8 A loads; B0 stays in flight
    u32x2 p;
    p[0] = cvtpk(ar[j][0], ar[j][1]);
    p[1] = cvtpk(ar[j][2], ar[j][3]);
    *(u32x2*)(lds + aw_idx[j]) = p;
  }
  asm volatile("s_waitcnt lgkmcnt(0)");
  __builtin_amdgcn_sched_barrier(0);

  int cur = 0;
  for (int kt = 0; kt < NKT; ++kt) {
    // only the current B-tile's 4 asyncs can be outstanding here (issued a full
    // iteration ago) -> cheap drain, ensures B[cur] is in LDS.
    asm volatile("s_waitcnt vmcnt(0)");
    __builtin_amdgcn_sched_barrier(0);
    if (kt < NKT - 1) {  // prefetch tile kt+1: stays in flight across both barriers
      int k1 = (kt + 1) * BK;
#pragma unroll
      for (int j = 0; j < 8; ++j) ar[j] = *(const f32x4*)(in + rowoff[j] + k1);
#pragma unroll
      for (int i = 0; i < 4; ++i)
        async_cp16(gB + k1 + (u64)i * 32 * EDIM,
                   lds + LB0 + (cur ^ 1) * 8192 + t * 8 + i * 2048);
    }
    __builtin_amdgcn_s_barrier();  // #1: A-lds writes (prev iter) + B[cur] visible
    int bbase = LB0 + cur * 8192;
#pragma unroll
    for (int kk = 0; kk < 64; kk += 32) {
      bf16x8 af[4], bfr[4];
#pragma unroll
      for (int mi = 0; mi < 4; ++mi)
        af[mi] = *(const bf16x8*)(lds + (ard[mi] ^ kk));
#pragma unroll
      for (int ni = 0; ni < 4; ++ni)
        bfr[ni] = *(const bf16x8*)(lds + bbase + (brd[ni] ^ kk));
#pragma unroll
      for (int mi = 0; mi < 4; ++mi)
#pragma unroll
        for (int ni = 0; ni < 4; ++ni)
          acc[mi][ni] = __builtin_amdgcn_mfma_f32_16x16x32_bf16(af[mi], bfr[ni],
                                                                acc[mi][ni], 0, 0, 0);
    }
    __builtin_amdgcn_s_barrier();  // #2: all waves done reading A-lds
    if (kt < NKT - 1) {            // A[kt+1] regs -> bf16 -> A-lds (single buffer)
#pragma unroll
      for (int j = 0; j < 8; ++j) {
        u32x2 p;
        p[0] = cvtpk(ar[j][0], ar[j][1]);
        p[1] = cvtpk(ar[j][2], ar[j][3]);
        *(u32x2*)(lds + aw_idx[j]) = p;
      }
      asm volatile("s_waitcnt lgkmcnt(0)");
      __builtin_amdgcn_sched_barrier(0);
    }
    cur ^= 1;
  }

  // ---- epilogue: acc -> Y[128][136] bf16 (overlays A|B0|start of B1), conv, store
  u16* Y = lds;
#pragma unroll
  for (int mi = 0; mi < 4; ++mi)
#pragma unroll
    for (int ni = 0; ni < 4; ++ni)
#pragma unroll
      for (int rr = 0; rr < 4; ++rr)
        Y[(wr * 64 + mi * 16 + lk * 4 + rr) * YSTR + wc * 64 + ni * 16 + lr] =
            f2b(acc[mi][ni][rr]);
  __syncthreads();

  bool edge = ((m0c + 2) >> 12) != ((m0c + 125) >> 12);
  if (edge)
    conv_store<true>(Y, t, m0c, n0, out);
  else
    conv_store<false>(Y, t, m0c, n0, out);
}

extern "C" void kernel_launch(void* const* d_in, const int* in_sizes, int n_in,
                              void* d_out, int out_size, void* d_ws, size_t ws_size,
                              hipStream_t stream) {
  const float* in   = (const float*)d_in[0];
  const float* Win  = (const float*)d_in[1];
  const float* Wout = (const float*)d_in[2];
  float* outp = (float*)d_out;

  u16* Mm = (u16*)d_ws;

  hipLaunchKernelGGL(gemm_m,   dim3(64), dim3(256), 0, stream, Wout, Win, Mm);
  hipLaunchKernelGGL(fused_gc, dim3(NWG), dim3(256), 0, stream, in, Mm, outp);
}